// Round 15
// baseline (208.944 us; speedup 1.0000x reference)
//
#include <hip/hip_runtime.h>
#include <math.h>

typedef unsigned int u32;
typedef unsigned long long u64;
typedef unsigned char u8;

#define K_TOT 8382
#define NCH 131      // 131 words of 64 rows
#define SC 4         // words per super-chunk (256 rows)
#define NSC ((NCH + SC - 1) / SC)   // 33 serial steps
#define CAP 1024     // per-TARGET-word off-diag entry capacity (global)
#define GCAP 32768   // per-level threshold-bin candidate capacity
#define IMGSZ 800.0f

__device__ __constant__ int LOFF[5] = {0, 120000, 150000, 157500, 159375};
__device__ __constant__ int LCNT[5] = {120000, 30000, 7500, 1875, 507};
__device__ __constant__ int KSEL[5] = {2000, 2000, 2000, 1875, 507};
__device__ __constant__ int SELB[5] = {0, 2000, 4000, 6000, 7875};
__device__ __constant__ int HBS[4] = {0, 118, 148, 156};    // k_hist block starts (levels 0..2)
__device__ __constant__ int GBS[6] = {0, 118, 148, 156, 158, 159};  // k_gather block starts

static __device__ __forceinline__ u32 fkey(float x) {
    u32 u = __float_as_uint(x);
    u32 m = (u32)(((int)u) >> 31) | 0x80000000u;
    return u ^ m;
}

static __device__ __forceinline__ int lvl_of(int s) {
    return (s < 2000) ? 0 : (s < 4000) ? 1 : (s < 6000) ? 2 : (s < 7875) ? 3 : 4;
}

// scalar-path readlanes (uniform lane index -> v_readlane)
static __device__ __forceinline__ u32 rdl32(u32 v, int j) {
    return (u32)__builtin_amdgcn_readlane((int)v, j);
}
static __device__ __forceinline__ u64 rdlane64(u64 v, int j) {
    u32 lo = (u32)__builtin_amdgcn_readlane((int)(u32)v, j);
    u32 hi = (u32)__builtin_amdgcn_readlane((int)(u32)(v >> 32), j);
    return ((u64)hi << 32) | (u64)lo;
}

// wave64 OR-reduce via DPP (row_shr 1/2/4/8 + bcast15 + bcast31); result in lane 63
static __device__ __forceinline__ u32 wor32(u32 x) {
    x |= (u32)__builtin_amdgcn_update_dpp(0, (int)x, 0x111, 0xf, 0xf, true);
    x |= (u32)__builtin_amdgcn_update_dpp(0, (int)x, 0x112, 0xf, 0xf, true);
    x |= (u32)__builtin_amdgcn_update_dpp(0, (int)x, 0x114, 0xf, 0xf, true);
    x |= (u32)__builtin_amdgcn_update_dpp(0, (int)x, 0x118, 0xf, 0xf, true);
    x |= (u32)__builtin_amdgcn_update_dpp(0, (int)x, 0x142, 0xa, 0xf, true);
    x |= (u32)__builtin_amdgcn_update_dpp(0, (int)x, 0x143, 0xc, 0xf, true);
    return x;
}

// wave64 inclusive scan (add) via shfl_up
static __device__ __forceinline__ u32 wscan_inc(u32 x, int lane) {
    for (int d = 1; d < 64; d <<= 1) {
        u32 v = (u32)__shfl_up((int)x, d, 64);
        if (lane >= d) x += v;
    }
    return x;
}

// Reverse-inclusive threshold scan, wave-hierarchical (2 barriers vs 23).
// hist[0..m-1] (shared), m in {1024, 2048}, block = 1024 threads.
// Finds top-down bin where suffix-cum >= need. Out: sv[0]=bin, sv[1]=ties to take.
static __device__ __forceinline__ void thresh_scan2(const u32* hist, int m, u32 need,
                                                    u32* sv, u32* wsum, int t) {
    int lane = t & 63, wv = t >> 6;
    u32 a, b = 0, s;
    if (m == 2048) {
        a = hist[2047 - 2 * t];
        b = hist[2046 - 2 * t];
        s = a + b;
    } else {
        a = hist[1023 - t];
        s = a;
    }
    u32 winc = wscan_inc(s, lane);
    if (lane == 63) wsum[wv] = winc;
    __syncthreads();
    u32 wexc = 0;
#pragma unroll
    for (int i = 0; i < 16; ++i) { u32 v = wsum[i]; if (i < wv) wexc += v; }
    u32 exc = wexc + winc - s;          // exclusive prefix of this thread's first element
    if (m == 2048) {
        u32 inc0 = exc + a;
        if (inc0 >= need && exc < need) { sv[0] = (u32)(2047 - 2 * t); sv[1] = need - exc; }
        u32 inc1 = inc0 + b;
        if (inc1 >= need && inc0 < need) { sv[0] = (u32)(2046 - 2 * t); sv[1] = need - inc0; }
    } else {
        u32 inc0 = exc + a;
        if (inc0 >= need && exc < need) { sv[0] = (u32)(1023 - t); sv[1] = need - exc; }
    }
    __syncthreads();
}

// exact reference-op-order box decode for selected slot s
static __device__ __forceinline__ void decode_one(int s, const float* __restrict__ scores,
                                                  const float4* __restrict__ deltas,
                                                  const float4* __restrict__ anchors,
                                                  const u32* __restrict__ sel,
                                                  float4* __restrict__ candB,
                                                  float* __restrict__ candS,
                                                  u32* __restrict__ candV,
                                                  u32* __restrict__ candA) {
    u32 a = sel[s];
    float4 an = anchors[a];
    float4 dl = deltas[a];
    float sc = scores[a];
    float w = __fsub_rn(an.z, an.x), h = __fsub_rn(an.w, an.y);
    float cx = __fadd_rn(an.x, __fmul_rn(0.5f, w));
    float cy = __fadd_rn(an.y, __fmul_rn(0.5f, h));
    const float CLIPV = (float)4.1351665567423563;  // log(1000/16) as f32
    float dw = fminf(dl.z, CLIPV);
    float dh = fminf(dl.w, CLIPV);
    float px = __fadd_rn(cx, __fmul_rn(dl.x, w));
    float py = __fadd_rn(cy, __fmul_rn(dl.y, h));
    float pw = __fmul_rn((float)exp((double)dw), w);
    float ph = __fmul_rn((float)exp((double)dh), h);
    float x1 = __fsub_rn(px, __fmul_rn(0.5f, pw));
    float y1 = __fsub_rn(py, __fmul_rn(0.5f, ph));
    float x2 = __fadd_rn(px, __fmul_rn(0.5f, pw));
    float y2 = __fadd_rn(py, __fmul_rn(0.5f, ph));
    x1 = fminf(fmaxf(x1, 0.0f), IMGSZ);
    y1 = fminf(fmaxf(y1, 0.0f), IMGSZ);
    x2 = fminf(fmaxf(x2, 0.0f), IMGSZ);
    y2 = fminf(fmaxf(y2, 0.0f), IMGSZ);
    bool valid = (__fsub_rn(x2, x1) >= 0.001f) && (__fsub_rn(y2, y1) >= 0.001f);
    candB[s] = make_float4(x1, y1, x2, y2);
    candS[s] = sc;
    candV[s] = valid ? 1u : 0u;
    candA[s] = a;
}

// ---------------- K1a: parallel coarse histogram (top 11 key bits), levels 0..2 ----------------
// (round-9 lesson: NO fused last-block threshold — __threadfence() in all 156 blocks on
//  multi-XCD gfx950 costs +39us. Consumers recompute thresholds inline instead.)
__global__ __launch_bounds__(1024) void k_hist(const float* __restrict__ scores,
                                               u32* __restrict__ hist3) {
    __shared__ u32 lh[2048];
    int t = threadIdx.x;
    lh[t] = 0; lh[t + 1024] = 0;
    __syncthreads();
    int b = blockIdx.x;
    int l = (b < HBS[1]) ? 0 : (b < HBS[2]) ? 1 : 2;
    int i = (b - HBS[l]) * 1024 + t;
    if (i < LCNT[l]) atomicAdd(&lh[fkey(scores[LOFF[l] + i]) >> 21], 1u);
    __syncthreads();
    u32* h = hist3 + l * 2048;
    if (lh[t]) atomicAdd(&h[t], lh[t]);
    if (lh[t + 1024]) atomicAdd(&h[t + 1024], lh[t + 1024]);
}

// ---------------- K1c: classify (coarse threshold recomputed inline per block) ----------------
__global__ __launch_bounds__(1024) void k_gather(const float* __restrict__ scores,
                                                 const u32* __restrict__ hist3,
                                                 u32* __restrict__ sel, u32* __restrict__ cgt,
                                                 u32* __restrict__ gcnt, u32* __restrict__ gidx,
                                                 u32* __restrict__ gkey) {
    __shared__ u32 lh[2048];
    __shared__ u32 wsum[16];
    __shared__ u32 sv[2];
    int b = blockIdx.x;
    int t = threadIdx.x;
    int l = (b < GBS[1]) ? 0 : (b < GBS[2]) ? 1 : (b < GBS[3]) ? 2 : (b < GBS[4]) ? 3 : 4;
    u32 b1 = 0;
    if (l < 3) {   // inline coarse threshold (all threads participate; no early returns yet)
        const u32* hg = hist3 + l * 2048;
        lh[t] = hg[t];
        lh[t + 1024] = hg[t + 1024];
        __syncthreads();
        thresh_scan2(lh, 2048, (u32)KSEL[l], sv, wsum, t);
        b1 = sv[0];
    }
    int i = (b - GBS[l]) * 1024 + t;
    if (i >= LCNT[l]) return;
    int off = LOFF[l], sb = SELB[l];
    if (l >= 3) { sel[sb + i] = (u32)(off + i); return; }  // take-all levels
    u32 ky = fkey(scores[off + i]);
    u32 top = ky >> 21;
    if (top > b1) {
        u32 p = atomicAdd(&cgt[l], 1u);
        sel[sb + p] = (u32)(off + i);          // set membership only; order fixed by rank later
    } else if (top == b1) {
        u32 e = atomicAdd(&gcnt[l], 1u);
        if (e < GCAP) { gidx[l * GCAP + e] = (u32)i; gkey[l * GCAP + e] = ky; }
    }
}

// ---------------- K1d: exact refine within threshold bin + fused decode ----------------
__global__ __launch_bounds__(1024) void k_final(const u32* __restrict__ gidx,
                                                const u32* __restrict__ gkey,
                                                const u32* __restrict__ gcnt,
                                                const u32* __restrict__ hist3,
                                                u32* __restrict__ sel,
                                                const float* __restrict__ scores,
                                                const float4* __restrict__ deltas,
                                                const float4* __restrict__ anchors,
                                                float4* __restrict__ candB,
                                                float* __restrict__ candS,
                                                u32* __restrict__ candV,
                                                u32* __restrict__ candA) {
    __shared__ u32 hist[2048];
    __shared__ u32 eqbuf[1024];
    __shared__ u32 wsum[16];
    __shared__ u32 sv[2];
    __shared__ u32 c2, ceq;
    int l = blockIdx.x;
    int t = threadIdx.x;
    int k = KSEL[l], sb = SELB[l], off = LOFF[l];
    if (l >= 3) {   // decode-only blocks (levels 3-4)
        for (int s2 = sb + t; s2 < sb + k; s2 += 1024)
            decode_one(s2, scores, deltas, anchors, sel, candB, candS, candV, candA);
        return;
    }
    // inline coarse threshold (replaces tinfo read)
    u32 b1, need;
    {
        const u32* hg = hist3 + l * 2048;
        hist[t] = hg[t];
        hist[t + 1024] = hg[t + 1024];
        __syncthreads();
        thresh_scan2(hist, 2048, (u32)KSEL[l], sv, wsum, t);
        b1 = sv[0]; need = sv[1];
    }
    u32 m = gcnt[l]; if (m > GCAP) m = GCAP;
    const u32* kb = gkey + l * GCAP;
    const u32* ib = gidx + l * GCAP;
    // mid 11 bits
    hist[t] = 0; hist[t + 1024] = 0; __syncthreads();
    for (u32 e = t; e < m; e += 1024) atomicAdd(&hist[(kb[e] >> 10) & 2047u], 1u);
    __syncthreads();
    thresh_scan2(hist, 2048, need, sv, wsum, t);
    u32 b2 = sv[0], need2 = sv[1];
    __syncthreads();
    // low 10 bits
    hist[t] = 0; __syncthreads();
    for (u32 e = t; e < m; e += 1024) {
        u32 ky = kb[e];
        if (((ky >> 10) & 2047u) == b2) atomicAdd(&hist[ky & 1023u], 1u);
    }
    __syncthreads();
    thresh_scan2(hist, 1024, need2, sv, wsum, t);
    u32 T = (b1 << 21) | (b2 << 10) | sv[0];
    u32 take = sv[1];
    if (t == 0) { c2 = 0; ceq = 0; }
    __syncthreads();
    u32 nGTbin = need - take;
    u32 base2 = (u32)sb + (u32)k - need;   // after strict-greater-bin entries
    for (u32 e = t; e < m; e += 1024) {
        u32 ky = kb[e];
        if (ky > T) { u32 p = atomicAdd(&c2, 1u); sel[base2 + p] = (u32)off + ib[e]; }
        else if (ky == T) { u32 q = atomicAdd(&ceq, 1u); if (q < 1024) eqbuf[q] = ib[e]; }
    }
    __syncthreads();
    if (t == 0) {
        int n = (ceq > 1024u) ? 1024 : (int)ceq;
        for (int a = 1; a < n; ++a) {  // ascending insertion sort; tie count tiny
            u32 v = eqbuf[a]; int bq = a - 1;
            while (bq >= 0 && eqbuf[bq] > v) { eqbuf[bq + 1] = eqbuf[bq]; --bq; }
            eqbuf[bq + 1] = v;
        }
        for (u32 q = 0; q < take; ++q) sel[base2 + nGTbin + q] = (u32)off + eqbuf[q];
    }
    __syncthreads();
    // fused decode of this level's rows (sel fully written: k_gather + this block)
    for (int s2 = sb + t; s2 < sb + k; s2 += 1024)
        decode_one(s2, scores, deltas, anchors, sel, candB, candS, candV, candA);
}

// ---------------- K3a: within-level rank (tiled pairwise count) ----------------
__global__ __launch_bounds__(256) void k_rank_lvl(const float* __restrict__ candS,
                                                  const u32* __restrict__ candA,
                                                  u32* __restrict__ Praw) {
    __shared__ u64 tile[256];
    int l = blockIdx.z;
    int cnt = KSEL[l], base = SELB[l];
    int tx = blockIdx.x * 256;
    int ty = blockIdx.y * 256;
    if (tx >= cnt || ty >= cnt) return;
    int t = threadIdx.x;
    u64 Aj = ~0ull;  // sentinel: never < any real key
    if (tx + t < cnt) {
        int j = base + tx + t;
        Aj = ((u64)(~fkey(candS[j])) << 32) | (u64)candA[j];
    }
    tile[t] = Aj;
    __syncthreads();
    int si = ty + t;
    if (si >= cnt) return;
    int s = base + si;
    u64 A = ((u64)(~fkey(candS[s])) << 32) | (u64)candA[s];
    int r = 0;
#pragma unroll 8
    for (int q = 0; q < 256; ++q) r += (tile[q] < A);
    if (r) atomicAdd(&Praw[s], (u32)r);
}

// ---------------- K3b: global rank by (masked score desc, position asc) ----------------
__global__ __launch_bounds__(256) void k_rank_glob(const float* __restrict__ candS,
                                                   const u32* __restrict__ candV,
                                                   const u32* __restrict__ Praw,
                                                   u32* __restrict__ rank) {
    __shared__ u64 colB[256];
    int t = threadIdx.x;
    int cj = blockIdx.x * 256 + t;
    u64 B = ~0ull;
    if (cj < K_TOT) {
        u32 smk = candV[cj] ? fkey(candS[cj]) : 0x007FFFFFu;  // fkey(-inf)
        u32 Pj = (u32)SELB[lvl_of(cj)] + Praw[cj];
        B = ((u64)(~smk) << 32) | (u64)Pj;
    }
    colB[t] = B;
    __syncthreads();
    int s = blockIdx.y * 256 + t;
    if (s >= K_TOT) return;
    u32 smk = candV[s] ? fkey(candS[s]) : 0x007FFFFFu;
    u32 Ps = (u32)SELB[lvl_of(s)] + Praw[s];
    u64 myB = ((u64)(~smk) << 32) | (u64)Ps;
    int cnt = 0;
#pragma unroll 8
    for (int j = 0; j < 256; ++j) cnt += (colB[j] < myB);
    if (cnt) atomicAdd(&rank[s], (u32)cnt);
}

// ---------------- K4: scatter into sorted order ----------------
// Reference's fmask slice is all zeros -> NMS on raw clipped boxes (no level offsets).
__global__ void k_scatter(const float4* __restrict__ candB, const float* __restrict__ candS,
                          const u32* __restrict__ candV, const u32* __restrict__ rank,
                          float4* __restrict__ sB, float* __restrict__ sArea,
                          float* __restrict__ sS, u32* __restrict__ sV) {
    int s = blockIdx.x * 256 + threadIdx.x;
    if (s >= K_TOT) return;
    u32 r = rank[s];
    float4 b = candB[s];
    float area = __fmul_rn(__fsub_rn(b.z, b.x), __fsub_rn(b.w, b.y));
    sB[r] = b; sArea[r] = area; sS[r] = candS[s]; sV[r] = candV[s];
}

// ---------------- K5: suppression bits -> packed entry lists (+ vwords/dmask ballots) ----------------
// off-diag: bucketed by TARGET word, 16B entries {src_row, bits}  (pull model).
// diag (intra-word): full diag[] row words; dmask via wave ballot (no atomics).
__global__ __launch_bounds__(256) void k_mask(const float4* __restrict__ sB,
                                              const float* __restrict__ sArea,
                                              const u32* __restrict__ sV,
                                              u64* __restrict__ vwords,
                                              u64* __restrict__ diag, u32* __restrict__ ecnt,
                                              ulonglong2* __restrict__ epack,
                                              u64* __restrict__ dmask) {
    __shared__ float4 cb[64];
    __shared__ float ca[64];
    int wd = blockIdx.x;   // target word (column chunk)
    int t = threadIdx.x;
    if (t < 64) {
        int j = wd * 64 + t;
        if (j < K_TOT) { cb[t] = sB[j]; ca[t] = sArea[j]; }
        else { cb[t] = make_float4(0.f, 0.f, 0.f, 0.f); ca[t] = 0.f; }
    }
    __syncthreads();
    int i = blockIdx.y * 256 + t;
    if (i >= K_TOT) return;
    int dwr = i >> 6;              // wave-uniform (i spans one aligned 64-row band per wave)
    if (wd < dwr) return;          // strictly upper-triangular
    float4 bi = sB[i];
    float ai = sArea[i];
    u64 bits = 0;
    int jbase = wd * 64;
    for (int j2 = 0; j2 < 64; ++j2) {
        int j = jbase + j2;
        if (j > i && j < K_TOT) {
            float4 bj = cb[j2];
            float ltx = fmaxf(bi.x, bj.x), lty = fmaxf(bi.y, bj.y);
            float rbx = fminf(bi.z, bj.z), rby = fminf(bi.w, bj.w);
            float wx = fmaxf(__fsub_rn(rbx, ltx), 0.0f);
            float wy = fmaxf(__fsub_rn(rby, lty), 0.0f);
            float inter = __fmul_rn(wx, wy);
            if (inter > 0.0f) {
                float uni = __fsub_rn(__fadd_rn(ai, ca[j2]), inter);
                float iou = inter / uni;  // IEEE f32 div, matches reference
                if (iou > 0.7f) bits |= (1ull << j2);
            }
        }
    }
    if (wd == dwr) {
        diag[i] = bits;                          // per-row intra-word suppressor word
        u64 vb = __ballot(sV[i] != 0u);          // wave-uniform branch: safe ballots
        u64 db = __ballot(bits != 0ull);
        if ((i & 63) == 0) { vwords[wd] = vb; dmask[wd] = db; }
    } else if (bits != 0ull) {
        u32 p = atomicAdd(&ecnt[wd], 1u);        // bucket by TARGET word (pull model)
        if (p < CAP) epack[wd * CAP + p] = make_ulonglong2((u64)i, bits);
    }
}

// ---------------- K6: 4-wave pipelined NMS scan over 256-row SUPER-CHUNKS ----------------
// Round-12 restructure: word k's incoming mask = EXTERNAL part (sources in earlier
// super-chunks — available right after the wait) + INTRA part (sources in words
// t0..t(k-1), ~5% of entries). All 4 external wave-OR reductions run as independent
// pipelined DPP chains (was: 4 serialized ~180cy chains = the dominant term); intra
// contributions are patched per word via ballot + sparse readlane loop. Word 0 has no
// intra sources (all sources < t0). Alive words are wave-uniform. Rare tails (cnt>128)
// keep the exact old slow path.
__global__ __launch_bounds__(512) void k_scan(const u64* __restrict__ diag,
                                              const u64* __restrict__ vwords,
                                              const u32* __restrict__ ecnt,
                                              const ulonglong2* __restrict__ tpack,
                                              const u64* __restrict__ dmask,
                                              const float4* __restrict__ sB,
                                              const float* __restrict__ sS,
                                              float* __restrict__ out) {
    __shared__ u64 sKeepArr[NSC * SC];   // 132 (index 131 = pad, stays benign)
    __shared__ u32 pc[NCH + 1];
    __shared__ u32 sProg;                // super-chunk units
    int t = threadIdx.x;
    int w = t >> 6, lane = t & 63;
    if (t == 0) sProg = 0;
    if (t < NSC * SC) sKeepArr[t] = 0;
    __syncthreads();
    if (w < 4) {
        for (int C = w; C < NSC; C += 4) {
            int w0 = C * SC;
            int t0 = w0, t1 = w0 + 1, t2 = w0 + 2, t3 = w0 + 3;
            bool x1v = t1 < NCH, x2v = t2 < NCH, x3v = t3 < NCH;
            int q1 = x1v ? t1 : 0, q2 = x2v ? t2 : 0, q3 = x3v ? t3 : 0;
            // ---- pre-stage from global (hidden under the pipeline wait) ----
            u32 c0 = ecnt[t0], c1 = x1v ? ecnt[q1] : 0, c2 = x2v ? ecnt[q2] : 0, c3 = x3v ? ecnt[q3] : 0;
            if (c0 > CAP) c0 = CAP;
            if (c1 > CAP) c1 = CAP;
            if (c2 > CAP) c2 = CAP;
            if (c3 > CAP) c3 = CAP;
            u64 vw0 = vwords[t0];
            u64 vw1 = x1v ? vwords[q1] : 0;
            u64 vw2 = x2v ? vwords[q2] : 0;
            u64 vw3 = x3v ? vwords[q3] : 0;
            u64 dmw0 = dmask[t0];
            u64 dmw1 = x1v ? dmask[q1] : 0;
            u64 dmw2 = x2v ? dmask[q2] : 0;
            u64 dmw3 = x3v ? dmask[q3] : 0;
            u64 D0 = diag[t0 * 64 + lane];
            u64 D1 = diag[q1 * 64 + lane];
            u64 D2 = diag[q2 * 64 + lane];
            u64 D3 = diag[q3 * 64 + lane];
            ulonglong2 E00 = tpack[(size_t)t0 * CAP + lane];
            ulonglong2 E01 = tpack[(size_t)t0 * CAP + 64 + lane];
            ulonglong2 E10 = tpack[(size_t)q1 * CAP + lane];
            ulonglong2 E11 = tpack[(size_t)q1 * CAP + 64 + lane];
            ulonglong2 E20 = tpack[(size_t)q2 * CAP + lane];
            ulonglong2 E21 = tpack[(size_t)q2 * CAP + 64 + lane];
            ulonglong2 E30 = tpack[(size_t)q3 * CAP + lane];
            ulonglong2 E31 = tpack[(size_t)q3 * CAP + 64 + lane];
            u32 s00 = (u32)E00.x, s01 = (u32)E01.x, s10 = (u32)E10.x, s11 = (u32)E11.x;
            u32 s20 = (u32)E20.x, s21 = (u32)E21.x, s30 = (u32)E30.x, s31 = (u32)E31.x;
            u32 h00 = s00 >> 6, h01 = s01 >> 6, h10 = s10 >> 6, h11 = s11 >> 6;
            u32 h20 = s20 >> 6, h21 = s21 >> 6, h30 = s30 >> 6, h31 = s31 >> 6;
            bool v00 = (u32)lane < c0, v01 = (u32)(lane + 64) < c0;
            bool v10 = (u32)lane < c1, v11 = (u32)(lane + 64) < c1;
            bool v20 = (u32)lane < c2, v21 = (u32)(lane + 64) < c2;
            bool v30 = (u32)lane < c3, v31 = (u32)(lane + 64) < c3;
            // intra-super-chunk source flags (deferred from external fold)
            bool d10 = (h10 == (u32)t0);
            bool d11 = (h11 == (u32)t0);
            bool d20 = (h20 == (u32)t0) || (h20 == (u32)t1);
            bool d21 = (h21 == (u32)t0) || (h21 == (u32)t1);
            bool d30 = (h30 == (u32)t0) || (h30 == (u32)t1) || (h30 == (u32)t2);
            bool d31 = (h31 == (u32)t0) || (h31 == (u32)t1) || (h31 == (u32)t2);
            // ---- wait for all earlier super-chunks (sleep while far from turn) ----
            if (C > 0) {
                for (;;) {
                    u32 p = __hip_atomic_load(&sProg, __ATOMIC_ACQUIRE, __HIP_MEMORY_SCOPE_WORKGROUP);
                    if (p >= (u32)C) break;
                    if ((u32)C > p + 1u) __builtin_amdgcn_s_sleep(2);
                }
            }
            // ---- external keep reads (clamped vs garbage lanes; deferred lanes excluded) ----
            u64 K00 = sKeepArr[h00 < (u32)NCH ? h00 : 0u];
            u64 K01 = sKeepArr[h01 < (u32)NCH ? h01 : 0u];
            u64 K10 = sKeepArr[h10 < (u32)NCH ? h10 : 0u];
            u64 K11 = sKeepArr[h11 < (u32)NCH ? h11 : 0u];
            u64 K20 = sKeepArr[h20 < (u32)NCH ? h20 : 0u];
            u64 K21 = sKeepArr[h21 < (u32)NCH ? h21 : 0u];
            u64 K30 = sKeepArr[h30 < (u32)NCH ? h30 : 0u];
            u64 K31 = sKeepArr[h31 < (u32)NCH ? h31 : 0u];
            // ---- external folds for ALL four words (word 0: all sources external) ----
            u64 m0 = 0, m1 = 0, m2 = 0, m3 = 0;
            if (v00 && ((K00 >> (s00 & 63u)) & 1ull)) m0 = E00.y;
            if (v01 && ((K01 >> (s01 & 63u)) & 1ull)) m0 |= E01.y;
            if (c0 > 128u) {   // word-0 tail: all sources external, fold now
                for (u32 e = 128u + (u32)lane; e < c0; e += 64u) {
                    ulonglong2 Et = tpack[(size_t)t0 * CAP + e];
                    u32 si = (u32)Et.x;
                    if ((sKeepArr[si >> 6] >> (si & 63u)) & 1ull) m0 |= Et.y;
                }
            }
            if (!d10 && v10 && ((K10 >> (s10 & 63u)) & 1ull)) m1 = E10.y;
            if (!d11 && v11 && ((K11 >> (s11 & 63u)) & 1ull)) m1 |= E11.y;
            if (!d20 && v20 && ((K20 >> (s20 & 63u)) & 1ull)) m2 = E20.y;
            if (!d21 && v21 && ((K21 >> (s21 & 63u)) & 1ull)) m2 |= E21.y;
            if (!d30 && v30 && ((K30 >> (s30 & 63u)) & 1ull)) m3 = E30.y;
            if (!d31 && v31 && ((K31 >> (s31 & 63u)) & 1ull)) m3 |= E31.y;
            // ---- 8 independent wave-OR chains (pipelined DPP) ----
            u32 r0l = wor32((u32)m0), r0h = wor32((u32)(m0 >> 32));
            u32 r1l = wor32((u32)m1), r1h = wor32((u32)(m1 >> 32));
            u32 r2l = wor32((u32)m2), r2h = wor32((u32)(m2 >> 32));
            u32 r3l = wor32((u32)m3), r3h = wor32((u32)(m3 >> 32));
            u64 inc0 = ((u64)rdl32(r0h, 63) << 32) | (u64)rdl32(r0l, 63);
            u64 ext1 = ((u64)rdl32(r1h, 63) << 32) | (u64)rdl32(r1l, 63);
            u64 ext2 = ((u64)rdl32(r2h, 63) << 32) | (u64)rdl32(r2l, 63);
            u64 ext3 = ((u64)rdl32(r3h, 63) << 32) | (u64)rdl32(r3l, 63);
            // ---- word 0 ----
            u64 alive0 = vw0 & ~inc0;
            if (dmw0) {
                u64 d = dmw0 & alive0;
                while (d) {
                    int j = __builtin_ctzll(d);
                    d &= d - 1;
                    if ((alive0 >> j) & 1ull) { alive0 &= ~rdlane64(D0, j); d &= alive0; }
                }
            }
            // ---- word 1: intra sources (h==t0) patched via sparse readlane loop ----
            u64 intra = 0;
            {
                u64 db = __ballot(d10 && v10 && ((alive0 >> (s10 & 63u)) & 1ull));
                while (db) { int j = __builtin_ctzll(db); db &= db - 1; intra |= rdlane64(E10.y, j); }
                db = __ballot(d11 && v11 && ((alive0 >> (s11 & 63u)) & 1ull));
                while (db) { int j = __builtin_ctzll(db); db &= db - 1; intra |= rdlane64(E11.y, j); }
            }
            u64 inc1 = ext1 | intra;
            if (c1 > 128u) {   // rare tail with intra selects
                u64 mt = 0;
                for (u32 e = 128u + (u32)lane; e < c1; e += 64u) {
                    ulonglong2 Et = tpack[(size_t)q1 * CAP + e];
                    u32 si = (u32)Et.x; u32 hh = si >> 6;
                    u64 kw = (hh == (u32)t0) ? alive0 : sKeepArr[hh];
                    if ((kw >> (si & 63u)) & 1ull) mt |= Et.y;
                }
                u32 tl = wor32((u32)mt), th = wor32((u32)(mt >> 32));
                inc1 |= ((u64)rdl32(th, 63) << 32) | (u64)rdl32(tl, 63);
            }
            u64 alive1 = vw1 & ~inc1;
            if (dmw1) {
                u64 d = dmw1 & alive1;
                while (d) {
                    int j = __builtin_ctzll(d);
                    d &= d - 1;
                    if ((alive1 >> j) & 1ull) { alive1 &= ~rdlane64(D1, j); d &= alive1; }
                }
            }
            // ---- word 2: intra sources (h in {t0,t1}) ----
            intra = 0;
            {
                u64 kwA = (h20 == (u32)t0) ? alive0 : alive1;   // valid only when d20
                u64 db = __ballot(d20 && v20 && ((kwA >> (s20 & 63u)) & 1ull));
                while (db) { int j = __builtin_ctzll(db); db &= db - 1; intra |= rdlane64(E20.y, j); }
                u64 kwB = (h21 == (u32)t0) ? alive0 : alive1;
                db = __ballot(d21 && v21 && ((kwB >> (s21 & 63u)) & 1ull));
                while (db) { int j = __builtin_ctzll(db); db &= db - 1; intra |= rdlane64(E21.y, j); }
            }
            u64 inc2 = ext2 | intra;
            if (c2 > 128u) {
                u64 mt = 0;
                for (u32 e = 128u + (u32)lane; e < c2; e += 64u) {
                    ulonglong2 Et = tpack[(size_t)q2 * CAP + e];
                    u32 si = (u32)Et.x; u32 hh = si >> 6;
                    u64 kw = (hh == (u32)t0) ? alive0 : (hh == (u32)t1) ? alive1 : sKeepArr[hh];
                    if ((kw >> (si & 63u)) & 1ull) mt |= Et.y;
                }
                u32 tl = wor32((u32)mt), th = wor32((u32)(mt >> 32));
                inc2 |= ((u64)rdl32(th, 63) << 32) | (u64)rdl32(tl, 63);
            }
            u64 alive2 = vw2 & ~inc2;
            if (dmw2) {
                u64 d = dmw2 & alive2;
                while (d) {
                    int j = __builtin_ctzll(d);
                    d &= d - 1;
                    if ((alive2 >> j) & 1ull) { alive2 &= ~rdlane64(D2, j); d &= alive2; }
                }
            }
            // ---- word 3: intra sources (h in {t0,t1,t2}) ----
            intra = 0;
            {
                u64 kwA = (h30 == (u32)t0) ? alive0 : (h30 == (u32)t1) ? alive1 : alive2;
                u64 db = __ballot(d30 && v30 && ((kwA >> (s30 & 63u)) & 1ull));
                while (db) { int j = __builtin_ctzll(db); db &= db - 1; intra |= rdlane64(E30.y, j); }
                u64 kwB = (h31 == (u32)t0) ? alive0 : (h31 == (u32)t1) ? alive1 : alive2;
                db = __ballot(d31 && v31 && ((kwB >> (s31 & 63u)) & 1ull));
                while (db) { int j = __builtin_ctzll(db); db &= db - 1; intra |= rdlane64(E31.y, j); }
            }
            u64 inc3 = ext3 | intra;
            if (c3 > 128u) {
                u64 mt = 0;
                for (u32 e = 128u + (u32)lane; e < c3; e += 64u) {
                    ulonglong2 Et = tpack[(size_t)q3 * CAP + e];
                    u32 si = (u32)Et.x; u32 hh = si >> 6;
                    u64 kw = (hh == (u32)t0) ? alive0 : (hh == (u32)t1) ? alive1
                           : (hh == (u32)t2) ? alive2 : sKeepArr[hh];
                    if ((kw >> (si & 63u)) & 1ull) mt |= Et.y;
                }
                u32 tl = wor32((u32)mt), th = wor32((u32)(mt >> 32));
                inc3 |= ((u64)rdl32(th, 63) << 32) | (u64)rdl32(tl, 63);
            }
            u64 alive3 = vw3 & ~inc3;
            if (dmw3) {
                u64 d = dmw3 & alive3;
                while (d) {
                    int j = __builtin_ctzll(d);
                    d &= d - 1;
                    if ((alive3 >> j) & 1ull) { alive3 &= ~rdlane64(D3, j); d &= alive3; }
                }
            }
            // ---- publish 4 words + release ----
            if (lane == 0) {
                sKeepArr[t0] = alive0;
                sKeepArr[t1] = alive1;
                sKeepArr[t2] = alive2;
                sKeepArr[t3] = alive3;
                __hip_atomic_store(&sProg, (u32)(C + 1), __ATOMIC_RELEASE, __HIP_MEMORY_SCOPE_WORKGROUP);
            }
        }
    }
    __syncthreads();
    // ---- fused output phase (all 512 threads) ----
    if (t < NCH) pc[t + 1] = (u32)__popcll(sKeepArr[t]);
    if (t == 0) pc[0] = 0;
    __syncthreads();
    for (int ofs = 1; ofs < NCH; ofs <<= 1) {   // Hillis-Steele inclusive scan over pc[1..NCH]
        int i = t + 1;
        u32 v = 0;
        bool p = (t < NCH) && (i - ofs >= 1);
        if (p) v = pc[i - ofs];
        __syncthreads();
        if (p) pc[i] += v;
        __syncthreads();
    }
    u32 nk = pc[NCH];
    for (int i = t; i < K_TOT; i += 512) {
        int wi = i >> 6, b = i & 63;
        u64 kw = sKeepArr[wi];
        u32 kb = pc[wi] + (u32)__popcll(kw & ((1ull << b) - 1ull));
        bool kp = (kw >> b) & 1ull;
        if (kp) {
            if (kb < 1000u) {
                float4 bx = sB[i];
                out[kb * 4 + 0] = bx.x; out[kb * 4 + 1] = bx.y;
                out[kb * 4 + 2] = bx.z; out[kb * 4 + 3] = bx.w;
                out[4000 + kb] = sS[i];
            }
        } else {
            u32 q = (u32)i - kb;
            u32 slot = nk + q;
            if (slot < 1000u) {
                float4 bx = sB[i];
                out[slot * 4 + 0] = bx.x; out[slot * 4 + 1] = bx.y;
                out[slot * 4 + 2] = bx.z; out[slot * 4 + 3] = bx.w;
                out[4000 + slot] = -INFINITY;
            }
        }
    }
}

// ---------------- workspace layout ----------------
static constexpr size_t al256(size_t x) { return (x + 255) & ~(size_t)255; }
static constexpr size_t KB4 = (size_t)K_TOT * 4;
static constexpr size_t KB16 = (size_t)K_TOT * 16;
// zeroed region:
static constexpr size_t O_RANK = 0;
static constexpr size_t O_PRAW = al256(O_RANK + KB4);
static constexpr size_t O_ECNT = al256(O_PRAW + KB4);
static constexpr size_t O_HIST = al256(O_ECNT + (size_t)NCH * 4);
static constexpr size_t O_CGT = al256(O_HIST + (size_t)3 * 2048 * 4);
static constexpr size_t O_GCNT = al256(O_CGT + 3 * 4);
static constexpr size_t MEMSET_BYTES = al256(O_GCNT + 3 * 4);
// non-zeroed region:
static constexpr size_t O_SEL = MEMSET_BYTES;
static constexpr size_t O_GIDX = al256(O_SEL + KB4);
static constexpr size_t O_GKEY = al256(O_GIDX + (size_t)3 * GCAP * 4);
static constexpr size_t O_CANDB = al256(O_GKEY + (size_t)3 * GCAP * 4);
static constexpr size_t O_CANDS = al256(O_CANDB + KB16);
static constexpr size_t O_CANDV = al256(O_CANDS + KB4);
static constexpr size_t O_CANDA = al256(O_CANDV + KB4);
static constexpr size_t O_SB = al256(O_CANDA + KB4);
static constexpr size_t O_SAREA = al256(O_SB + KB16);
static constexpr size_t O_SS = al256(O_SAREA + KB4);
static constexpr size_t O_SV = al256(O_SS + KB4);
static constexpr size_t O_VW = al256(O_SV + KB4);
static constexpr size_t O_DMASK = al256(O_VW + (size_t)NCH * 8);
static constexpr size_t O_DIAG = al256(O_DMASK + (size_t)NCH * 8);
static constexpr size_t O_EPACK = al256(O_DIAG + (size_t)(NCH * 64) * 8);

extern "C" void kernel_launch(void* const* d_in, const int* in_sizes, int n_in,
                              void* d_out, int out_size, void* d_ws, size_t ws_size,
                              hipStream_t stream) {
    const float* scores = (const float*)d_in[0];
    const float4* deltas = (const float4*)d_in[1];
    const float4* anchors = (const float4*)d_in[2];
    float* out = (float*)d_out;
    char* ws = (char*)d_ws;

    u32* rank = (u32*)(ws + O_RANK);
    u32* Praw = (u32*)(ws + O_PRAW);
    u32* ecnt = (u32*)(ws + O_ECNT);
    u32* hist3 = (u32*)(ws + O_HIST);
    u32* cgt = (u32*)(ws + O_CGT);
    u32* gcnt = (u32*)(ws + O_GCNT);
    u32* sel = (u32*)(ws + O_SEL);
    u32* gidx = (u32*)(ws + O_GIDX);
    u32* gkey = (u32*)(ws + O_GKEY);
    float4* candB = (float4*)(ws + O_CANDB);
    float* candS = (float*)(ws + O_CANDS);
    u32* candV = (u32*)(ws + O_CANDV);
    u32* candA = (u32*)(ws + O_CANDA);
    float4* sB = (float4*)(ws + O_SB);
    float* sArea = (float*)(ws + O_SAREA);
    float* sS = (float*)(ws + O_SS);
    u32* sV = (u32*)(ws + O_SV);
    u64* vwords = (u64*)(ws + O_VW);
    u64* dmask = (u64*)(ws + O_DMASK);
    u64* diag = (u64*)(ws + O_DIAG);
    ulonglong2* epack = (ulonglong2*)(ws + O_EPACK);

    hipMemsetAsync(ws, 0, MEMSET_BYTES, stream);

    const int NBLK = (K_TOT + 255) / 256;  // 33
    k_hist<<<156, 1024, 0, stream>>>(scores, hist3);
    k_gather<<<159, 1024, 0, stream>>>(scores, hist3, sel, cgt, gcnt, gidx, gkey);
    k_final<<<5, 1024, 0, stream>>>(gidx, gkey, gcnt, hist3, sel,
                                    scores, deltas, anchors, candB, candS, candV, candA);
    k_rank_lvl<<<dim3(8, 8, 5), 256, 0, stream>>>(candS, candA, Praw);
    k_rank_glob<<<dim3(NBLK, NBLK), 256, 0, stream>>>(candS, candV, Praw, rank);
    k_scatter<<<NBLK, 256, 0, stream>>>(candB, candS, candV, rank, sB, sArea, sS, sV);
    k_mask<<<dim3(NCH, NBLK), 256, 0, stream>>>(sB, sArea, sV, vwords, diag, ecnt, epack, dmask);
    k_scan<<<1, 512, 0, stream>>>(diag, vwords, ecnt, epack, dmask, sB, sS, out);
}

// Round 16
// 197.153 us; speedup vs baseline: 1.0598x; 1.0598x over previous
//
#include <hip/hip_runtime.h>
#include <math.h>

typedef unsigned int u32;
typedef unsigned long long u64;
typedef unsigned char u8;

#define K_TOT 8382
#define NCH 131      // 131 words of 64 rows
#define SC 4         // words per super-chunk (256 rows)
#define NSC ((NCH + SC - 1) / SC)   // 33 serial steps
#define CAP 1024     // per-TARGET-word off-diag entry capacity (global)
#define GCAP 32768   // per-level threshold-bin candidate capacity
#define IMGSZ 800.0f

__device__ __constant__ int LOFF[5] = {0, 120000, 150000, 157500, 159375};
__device__ __constant__ int LCNT[5] = {120000, 30000, 7500, 1875, 507};
__device__ __constant__ int KSEL[5] = {2000, 2000, 2000, 1875, 507};
__device__ __constant__ int SELB[5] = {0, 2000, 4000, 6000, 7875};
__device__ __constant__ int HBS[4] = {0, 118, 148, 156};    // k_hist block starts (levels 0..2)
__device__ __constant__ int GBS[6] = {0, 118, 148, 156, 158, 159};  // k_gather block starts

static __device__ __forceinline__ u32 fkey(float x) {
    u32 u = __float_as_uint(x);
    u32 m = (u32)(((int)u) >> 31) | 0x80000000u;
    return u ^ m;
}

static __device__ __forceinline__ int lvl_of(int s) {
    return (s < 2000) ? 0 : (s < 4000) ? 1 : (s < 6000) ? 2 : (s < 7875) ? 3 : 4;
}

// scalar-path readlanes (uniform lane index -> v_readlane)
static __device__ __forceinline__ u32 rdl32(u32 v, int j) {
    return (u32)__builtin_amdgcn_readlane((int)v, j);
}
static __device__ __forceinline__ u64 rdlane64(u64 v, int j) {
    u32 lo = (u32)__builtin_amdgcn_readlane((int)(u32)v, j);
    u32 hi = (u32)__builtin_amdgcn_readlane((int)(u32)(v >> 32), j);
    return ((u64)hi << 32) | (u64)lo;
}

// wave64 OR-reduce via DPP (row_shr 1/2/4/8 + bcast15 + bcast31); result in lane 63
static __device__ __forceinline__ u32 wor32(u32 x) {
    x |= (u32)__builtin_amdgcn_update_dpp(0, (int)x, 0x111, 0xf, 0xf, true);
    x |= (u32)__builtin_amdgcn_update_dpp(0, (int)x, 0x112, 0xf, 0xf, true);
    x |= (u32)__builtin_amdgcn_update_dpp(0, (int)x, 0x114, 0xf, 0xf, true);
    x |= (u32)__builtin_amdgcn_update_dpp(0, (int)x, 0x118, 0xf, 0xf, true);
    x |= (u32)__builtin_amdgcn_update_dpp(0, (int)x, 0x142, 0xa, 0xf, true);
    x |= (u32)__builtin_amdgcn_update_dpp(0, (int)x, 0x143, 0xc, 0xf, true);
    return x;
}

// wave64 inclusive scan (add) via shfl_up
static __device__ __forceinline__ u32 wscan_inc(u32 x, int lane) {
    for (int d = 1; d < 64; d <<= 1) {
        u32 v = (u32)__shfl_up((int)x, d, 64);
        if (lane >= d) x += v;
    }
    return x;
}

// Reverse-inclusive threshold scan, wave-hierarchical (2 barriers vs 23).
// hist[0..m-1] (shared), m in {1024, 2048}, block = 1024 threads.
// Finds top-down bin where suffix-cum >= need. Out: sv[0]=bin, sv[1]=ties to take.
static __device__ __forceinline__ void thresh_scan2(const u32* hist, int m, u32 need,
                                                    u32* sv, u32* wsum, int t) {
    int lane = t & 63, wv = t >> 6;
    u32 a, b = 0, s;
    if (m == 2048) {
        a = hist[2047 - 2 * t];
        b = hist[2046 - 2 * t];
        s = a + b;
    } else {
        a = hist[1023 - t];
        s = a;
    }
    u32 winc = wscan_inc(s, lane);
    if (lane == 63) wsum[wv] = winc;
    __syncthreads();
    u32 wexc = 0;
#pragma unroll
    for (int i = 0; i < 16; ++i) { u32 v = wsum[i]; if (i < wv) wexc += v; }
    u32 exc = wexc + winc - s;          // exclusive prefix of this thread's first element
    if (m == 2048) {
        u32 inc0 = exc + a;
        if (inc0 >= need && exc < need) { sv[0] = (u32)(2047 - 2 * t); sv[1] = need - exc; }
        u32 inc1 = inc0 + b;
        if (inc1 >= need && inc0 < need) { sv[0] = (u32)(2046 - 2 * t); sv[1] = need - inc0; }
    } else {
        u32 inc0 = exc + a;
        if (inc0 >= need && exc < need) { sv[0] = (u32)(1023 - t); sv[1] = need - exc; }
    }
    __syncthreads();
}

// exact reference-op-order box decode for selected slot s
static __device__ __forceinline__ void decode_one(int s, const float* __restrict__ scores,
                                                  const float4* __restrict__ deltas,
                                                  const float4* __restrict__ anchors,
                                                  const u32* __restrict__ sel,
                                                  float4* __restrict__ candB,
                                                  float* __restrict__ candS,
                                                  u32* __restrict__ candV,
                                                  u32* __restrict__ candA) {
    u32 a = sel[s];
    float4 an = anchors[a];
    float4 dl = deltas[a];
    float sc = scores[a];
    float w = __fsub_rn(an.z, an.x), h = __fsub_rn(an.w, an.y);
    float cx = __fadd_rn(an.x, __fmul_rn(0.5f, w));
    float cy = __fadd_rn(an.y, __fmul_rn(0.5f, h));
    const float CLIPV = (float)4.1351665567423563;  // log(1000/16) as f32
    float dw = fminf(dl.z, CLIPV);
    float dh = fminf(dl.w, CLIPV);
    float px = __fadd_rn(cx, __fmul_rn(dl.x, w));
    float py = __fadd_rn(cy, __fmul_rn(dl.y, h));
    float pw = __fmul_rn((float)exp((double)dw), w);
    float ph = __fmul_rn((float)exp((double)dh), h);
    float x1 = __fsub_rn(px, __fmul_rn(0.5f, pw));
    float y1 = __fsub_rn(py, __fmul_rn(0.5f, ph));
    float x2 = __fadd_rn(px, __fmul_rn(0.5f, pw));
    float y2 = __fadd_rn(py, __fmul_rn(0.5f, ph));
    x1 = fminf(fmaxf(x1, 0.0f), IMGSZ);
    y1 = fminf(fmaxf(y1, 0.0f), IMGSZ);
    x2 = fminf(fmaxf(x2, 0.0f), IMGSZ);
    y2 = fminf(fmaxf(y2, 0.0f), IMGSZ);
    bool valid = (__fsub_rn(x2, x1) >= 0.001f) && (__fsub_rn(y2, y1) >= 0.001f);
    candB[s] = make_float4(x1, y1, x2, y2);
    candS[s] = sc;
    candV[s] = valid ? 1u : 0u;
    candA[s] = a;
}

// ---------------- K1a: parallel coarse histogram (top 11 key bits), levels 0..2 ----------------
// (round-9 lesson: NO fused last-block threshold — __threadfence() in all 156 blocks on
//  multi-XCD gfx950 costs +39us. Consumers recompute thresholds inline instead.)
__global__ __launch_bounds__(1024) void k_hist(const float* __restrict__ scores,
                                               u32* __restrict__ hist3) {
    __shared__ u32 lh[2048];
    int t = threadIdx.x;
    lh[t] = 0; lh[t + 1024] = 0;
    __syncthreads();
    int b = blockIdx.x;
    int l = (b < HBS[1]) ? 0 : (b < HBS[2]) ? 1 : 2;
    int i = (b - HBS[l]) * 1024 + t;
    if (i < LCNT[l]) atomicAdd(&lh[fkey(scores[LOFF[l] + i]) >> 21], 1u);
    __syncthreads();
    u32* h = hist3 + l * 2048;
    if (lh[t]) atomicAdd(&h[t], lh[t]);
    if (lh[t + 1024]) atomicAdd(&h[t + 1024], lh[t + 1024]);
}

// ---------------- K1c: classify (coarse threshold recomputed inline per block) ----------------
__global__ __launch_bounds__(1024) void k_gather(const float* __restrict__ scores,
                                                 const u32* __restrict__ hist3,
                                                 u32* __restrict__ sel, u32* __restrict__ cgt,
                                                 u32* __restrict__ gcnt, u32* __restrict__ gidx,
                                                 u32* __restrict__ gkey) {
    __shared__ u32 lh[2048];
    __shared__ u32 wsum[16];
    __shared__ u32 sv[2];
    int b = blockIdx.x;
    int t = threadIdx.x;
    int l = (b < GBS[1]) ? 0 : (b < GBS[2]) ? 1 : (b < GBS[3]) ? 2 : (b < GBS[4]) ? 3 : 4;
    u32 b1 = 0;
    if (l < 3) {   // inline coarse threshold (all threads participate; no early returns yet)
        const u32* hg = hist3 + l * 2048;
        lh[t] = hg[t];
        lh[t + 1024] = hg[t + 1024];
        __syncthreads();
        thresh_scan2(lh, 2048, (u32)KSEL[l], sv, wsum, t);
        b1 = sv[0];
    }
    int i = (b - GBS[l]) * 1024 + t;
    if (i >= LCNT[l]) return;
    int off = LOFF[l], sb = SELB[l];
    if (l >= 3) { sel[sb + i] = (u32)(off + i); return; }  // take-all levels
    u32 ky = fkey(scores[off + i]);
    u32 top = ky >> 21;
    if (top > b1) {
        u32 p = atomicAdd(&cgt[l], 1u);
        sel[sb + p] = (u32)(off + i);          // set membership only; order fixed by rank later
    } else if (top == b1) {
        u32 e = atomicAdd(&gcnt[l], 1u);
        if (e < GCAP) { gidx[l * GCAP + e] = (u32)i; gkey[l * GCAP + e] = ky; }
    }
}

// ---------------- K1d: exact refine within threshold bin + fused decode ----------------
__global__ __launch_bounds__(1024) void k_final(const u32* __restrict__ gidx,
                                                const u32* __restrict__ gkey,
                                                const u32* __restrict__ gcnt,
                                                const u32* __restrict__ hist3,
                                                u32* __restrict__ sel,
                                                const float* __restrict__ scores,
                                                const float4* __restrict__ deltas,
                                                const float4* __restrict__ anchors,
                                                float4* __restrict__ candB,
                                                float* __restrict__ candS,
                                                u32* __restrict__ candV,
                                                u32* __restrict__ candA) {
    __shared__ u32 hist[2048];
    __shared__ u32 eqbuf[1024];
    __shared__ u32 wsum[16];
    __shared__ u32 sv[2];
    __shared__ u32 c2, ceq;
    int l = blockIdx.x;
    int t = threadIdx.x;
    int k = KSEL[l], sb = SELB[l], off = LOFF[l];
    if (l >= 3) {   // decode-only blocks (levels 3-4)
        for (int s2 = sb + t; s2 < sb + k; s2 += 1024)
            decode_one(s2, scores, deltas, anchors, sel, candB, candS, candV, candA);
        return;
    }
    // inline coarse threshold (replaces tinfo read)
    u32 b1, need;
    {
        const u32* hg = hist3 + l * 2048;
        hist[t] = hg[t];
        hist[t + 1024] = hg[t + 1024];
        __syncthreads();
        thresh_scan2(hist, 2048, (u32)KSEL[l], sv, wsum, t);
        b1 = sv[0]; need = sv[1];
    }
    u32 m = gcnt[l]; if (m > GCAP) m = GCAP;
    const u32* kb = gkey + l * GCAP;
    const u32* ib = gidx + l * GCAP;
    // mid 11 bits
    hist[t] = 0; hist[t + 1024] = 0; __syncthreads();
    for (u32 e = t; e < m; e += 1024) atomicAdd(&hist[(kb[e] >> 10) & 2047u], 1u);
    __syncthreads();
    thresh_scan2(hist, 2048, need, sv, wsum, t);
    u32 b2 = sv[0], need2 = sv[1];
    __syncthreads();
    // low 10 bits
    hist[t] = 0; __syncthreads();
    for (u32 e = t; e < m; e += 1024) {
        u32 ky = kb[e];
        if (((ky >> 10) & 2047u) == b2) atomicAdd(&hist[ky & 1023u], 1u);
    }
    __syncthreads();
    thresh_scan2(hist, 1024, need2, sv, wsum, t);
    u32 T = (b1 << 21) | (b2 << 10) | sv[0];
    u32 take = sv[1];
    if (t == 0) { c2 = 0; ceq = 0; }
    __syncthreads();
    u32 nGTbin = need - take;
    u32 base2 = (u32)sb + (u32)k - need;   // after strict-greater-bin entries
    for (u32 e = t; e < m; e += 1024) {
        u32 ky = kb[e];
        if (ky > T) { u32 p = atomicAdd(&c2, 1u); sel[base2 + p] = (u32)off + ib[e]; }
        else if (ky == T) { u32 q = atomicAdd(&ceq, 1u); if (q < 1024) eqbuf[q] = ib[e]; }
    }
    __syncthreads();
    if (t == 0) {
        int n = (ceq > 1024u) ? 1024 : (int)ceq;
        for (int a = 1; a < n; ++a) {  // ascending insertion sort; tie count tiny
            u32 v = eqbuf[a]; int bq = a - 1;
            while (bq >= 0 && eqbuf[bq] > v) { eqbuf[bq + 1] = eqbuf[bq]; --bq; }
            eqbuf[bq + 1] = v;
        }
        for (u32 q = 0; q < take; ++q) sel[base2 + nGTbin + q] = (u32)off + eqbuf[q];
    }
    __syncthreads();
    // fused decode of this level's rows (sel fully written: k_gather + this block)
    for (int s2 = sb + t; s2 < sb + k; s2 += 1024)
        decode_one(s2, scores, deltas, anchors, sel, candB, candS, candV, candA);
}

// ---------------- K3a: within-level rank (tiled pairwise count) ----------------
__global__ __launch_bounds__(256) void k_rank_lvl(const float* __restrict__ candS,
                                                  const u32* __restrict__ candA,
                                                  u32* __restrict__ Praw) {
    __shared__ u64 tile[256];
    int l = blockIdx.z;
    int cnt = KSEL[l], base = SELB[l];
    int tx = blockIdx.x * 256;
    int ty = blockIdx.y * 256;
    if (tx >= cnt || ty >= cnt) return;
    int t = threadIdx.x;
    u64 Aj = ~0ull;  // sentinel: never < any real key
    if (tx + t < cnt) {
        int j = base + tx + t;
        Aj = ((u64)(~fkey(candS[j])) << 32) | (u64)candA[j];
    }
    tile[t] = Aj;
    __syncthreads();
    int si = ty + t;
    if (si >= cnt) return;
    int s = base + si;
    u64 A = ((u64)(~fkey(candS[s])) << 32) | (u64)candA[s];
    int r = 0;
#pragma unroll 8
    for (int q = 0; q < 256; ++q) r += (tile[q] < A);
    if (r) atomicAdd(&Praw[s], (u32)r);
}

// ---------------- K3b: global rank by (masked score desc, position asc) ----------------
__global__ __launch_bounds__(256) void k_rank_glob(const float* __restrict__ candS,
                                                   const u32* __restrict__ candV,
                                                   const u32* __restrict__ Praw,
                                                   u32* __restrict__ rank) {
    __shared__ u64 colB[256];
    int t = threadIdx.x;
    int cj = blockIdx.x * 256 + t;
    u64 B = ~0ull;
    if (cj < K_TOT) {
        u32 smk = candV[cj] ? fkey(candS[cj]) : 0x007FFFFFu;  // fkey(-inf)
        u32 Pj = (u32)SELB[lvl_of(cj)] + Praw[cj];
        B = ((u64)(~smk) << 32) | (u64)Pj;
    }
    colB[t] = B;
    __syncthreads();
    int s = blockIdx.y * 256 + t;
    if (s >= K_TOT) return;
    u32 smk = candV[s] ? fkey(candS[s]) : 0x007FFFFFu;
    u32 Ps = (u32)SELB[lvl_of(s)] + Praw[s];
    u64 myB = ((u64)(~smk) << 32) | (u64)Ps;
    int cnt = 0;
#pragma unroll 8
    for (int j = 0; j < 256; ++j) cnt += (colB[j] < myB);
    if (cnt) atomicAdd(&rank[s], (u32)cnt);
}

// ---------------- K4: scatter into sorted order ----------------
// Reference's fmask slice is all zeros -> NMS on raw clipped boxes (no level offsets).
__global__ void k_scatter(const float4* __restrict__ candB, const float* __restrict__ candS,
                          const u32* __restrict__ candV, const u32* __restrict__ rank,
                          float4* __restrict__ sB, float* __restrict__ sArea,
                          float* __restrict__ sS, u32* __restrict__ sV) {
    int s = blockIdx.x * 256 + threadIdx.x;
    if (s >= K_TOT) return;
    u32 r = rank[s];
    float4 b = candB[s];
    float area = __fmul_rn(__fsub_rn(b.z, b.x), __fsub_rn(b.w, b.y));
    sB[r] = b; sArea[r] = area; sS[r] = candS[s]; sV[r] = candV[s];
}

// ---------------- K5: suppression bits -> packed entry lists (+ vwords/dmask ballots) ----------------
// off-diag: bucketed by TARGET word, 16B entries {src_row, bits}  (pull model).
// diag (intra-word): full diag[] row words; dmask via wave ballot (no atomics).
__global__ __launch_bounds__(256) void k_mask(const float4* __restrict__ sB,
                                              const float* __restrict__ sArea,
                                              const u32* __restrict__ sV,
                                              u64* __restrict__ vwords,
                                              u64* __restrict__ diag, u32* __restrict__ ecnt,
                                              ulonglong2* __restrict__ epack,
                                              u64* __restrict__ dmask) {
    __shared__ float4 cb[64];
    __shared__ float ca[64];
    int wd = blockIdx.x;   // target word (column chunk)
    int t = threadIdx.x;
    if (t < 64) {
        int j = wd * 64 + t;
        if (j < K_TOT) { cb[t] = sB[j]; ca[t] = sArea[j]; }
        else { cb[t] = make_float4(0.f, 0.f, 0.f, 0.f); ca[t] = 0.f; }
    }
    __syncthreads();
    int i = blockIdx.y * 256 + t;
    if (i >= K_TOT) return;
    int dwr = i >> 6;              // wave-uniform (i spans one aligned 64-row band per wave)
    if (wd < dwr) return;          // strictly upper-triangular
    float4 bi = sB[i];
    float ai = sArea[i];
    u64 bits = 0;
    int jbase = wd * 64;
    for (int j2 = 0; j2 < 64; ++j2) {
        int j = jbase + j2;
        if (j > i && j < K_TOT) {
            float4 bj = cb[j2];
            float ltx = fmaxf(bi.x, bj.x), lty = fmaxf(bi.y, bj.y);
            float rbx = fminf(bi.z, bj.z), rby = fminf(bi.w, bj.w);
            float wx = fmaxf(__fsub_rn(rbx, ltx), 0.0f);
            float wy = fmaxf(__fsub_rn(rby, lty), 0.0f);
            float inter = __fmul_rn(wx, wy);
            if (inter > 0.0f) {
                float uni = __fsub_rn(__fadd_rn(ai, ca[j2]), inter);
                float iou = inter / uni;  // IEEE f32 div, matches reference
                if (iou > 0.7f) bits |= (1ull << j2);
            }
        }
    }
    if (wd == dwr) {
        diag[i] = bits;                          // per-row intra-word suppressor word
        u64 vb = __ballot(sV[i] != 0u);          // wave-uniform branch: safe ballots
        u64 db = __ballot(bits != 0ull);
        if ((i & 63) == 0) { vwords[wd] = vb; dmask[wd] = db; }
    } else if (bits != 0ull) {
        u32 p = atomicAdd(&ecnt[wd], 1u);        // bucket by TARGET word (pull model)
        if (p < CAP) epack[wd * CAP + p] = make_ulonglong2((u64)i, bits);
    }
}

// ---------------- K6: 4-wave pipelined NMS scan over 256-row SUPER-CHUNKS ----------------
// (round-8/12 proven loop body, 44.4us measured x3. Round-15 lesson: the external/intra
//  wor32 split REGRESSED to 67us — SGPR pressure + added ballots beat any DPP pipelining
//  gain. This serial resolve chain ~340ns/word is the structural floor for this scheme.)
__global__ __launch_bounds__(512) void k_scan(const u64* __restrict__ diag,
                                              const u64* __restrict__ vwords,
                                              const u32* __restrict__ ecnt,
                                              const ulonglong2* __restrict__ tpack,
                                              const u64* __restrict__ dmask,
                                              const float4* __restrict__ sB,
                                              const float* __restrict__ sS,
                                              float* __restrict__ out) {
    __shared__ u64 sKeepArr[NSC * SC];   // 132 (index 131 = pad, stays benign)
    __shared__ u32 pc[NCH + 1];
    __shared__ u32 sProg;                // super-chunk units
    int t = threadIdx.x;
    int w = t >> 6, lane = t & 63;
    if (t == 0) sProg = 0;
    if (t < NSC * SC) sKeepArr[t] = 0;
    __syncthreads();
    if (w < 4) {
        for (int C = w; C < NSC; C += 4) {
            int w0 = C * SC;
            int t0 = w0, t1 = w0 + 1, t2 = w0 + 2, t3 = w0 + 3;
            bool x1v = t1 < NCH, x2v = t2 < NCH, x3v = t3 < NCH;
            int q1 = x1v ? t1 : 0, q2 = x2v ? t2 : 0, q3 = x3v ? t3 : 0;
            // ---- pre-stage from global (hidden under the pipeline wait) ----
            u32 c0 = ecnt[t0], c1 = x1v ? ecnt[q1] : 0, c2 = x2v ? ecnt[q2] : 0, c3 = x3v ? ecnt[q3] : 0;
            if (c0 > CAP) c0 = CAP;
            if (c1 > CAP) c1 = CAP;
            if (c2 > CAP) c2 = CAP;
            if (c3 > CAP) c3 = CAP;
            u64 vw0 = vwords[t0];
            u64 vw1 = x1v ? vwords[q1] : 0;
            u64 vw2 = x2v ? vwords[q2] : 0;
            u64 vw3 = x3v ? vwords[q3] : 0;
            u64 dmw0 = dmask[t0];
            u64 dmw1 = x1v ? dmask[q1] : 0;
            u64 dmw2 = x2v ? dmask[q2] : 0;
            u64 dmw3 = x3v ? dmask[q3] : 0;
            u64 D0 = diag[t0 * 64 + lane];
            u64 D1 = diag[q1 * 64 + lane];
            u64 D2 = diag[q2 * 64 + lane];
            u64 D3 = diag[q3 * 64 + lane];
            ulonglong2 E00 = tpack[(size_t)t0 * CAP + lane];
            ulonglong2 E01 = tpack[(size_t)t0 * CAP + 64 + lane];
            ulonglong2 E10 = tpack[(size_t)q1 * CAP + lane];
            ulonglong2 E11 = tpack[(size_t)q1 * CAP + 64 + lane];
            ulonglong2 E20 = tpack[(size_t)q2 * CAP + lane];
            ulonglong2 E21 = tpack[(size_t)q2 * CAP + 64 + lane];
            ulonglong2 E30 = tpack[(size_t)q3 * CAP + lane];
            ulonglong2 E31 = tpack[(size_t)q3 * CAP + 64 + lane];
            u32 s00 = (u32)E00.x, s01 = (u32)E01.x, s10 = (u32)E10.x, s11 = (u32)E11.x;
            u32 s20 = (u32)E20.x, s21 = (u32)E21.x, s30 = (u32)E30.x, s31 = (u32)E31.x;
            u32 h00 = s00 >> 6, h01 = s01 >> 6, h10 = s10 >> 6, h11 = s11 >> 6;
            u32 h20 = s20 >> 6, h21 = s21 >> 6, h30 = s30 >> 6, h31 = s31 >> 6;
            // ---- wait for all earlier super-chunks (sleep while far from turn) ----
            if (C > 0) {
                for (;;) {
                    u32 p = __hip_atomic_load(&sProg, __ATOMIC_ACQUIRE, __HIP_MEMORY_SCOPE_WORKGROUP);
                    if (p >= (u32)C) break;
                    if ((u32)C > p + 1u) __builtin_amdgcn_s_sleep(2);
                }
            }
            // ---- external keep reads (clamped vs garbage lanes; intra-chunk overridden) ----
            u64 K00 = sKeepArr[h00 < (u32)NCH ? h00 : 0u];
            u64 K01 = sKeepArr[h01 < (u32)NCH ? h01 : 0u];
            u64 K10 = sKeepArr[h10 < (u32)NCH ? h10 : 0u];
            u64 K11 = sKeepArr[h11 < (u32)NCH ? h11 : 0u];
            u64 K20 = sKeepArr[h20 < (u32)NCH ? h20 : 0u];
            u64 K21 = sKeepArr[h21 < (u32)NCH ? h21 : 0u];
            u64 K30 = sKeepArr[h30 < (u32)NCH ? h30 : 0u];
            u64 K31 = sKeepArr[h31 < (u32)NCH ? h31 : 0u];
            // ---- word 0 (all sources external) ----
            u64 m = 0;
            if ((u32)lane < c0 && ((K00 >> (s00 & 63u)) & 1ull)) m = E00.y;
            if ((u32)(lane + 64) < c0 && ((K01 >> (s01 & 63u)) & 1ull)) m |= E01.y;
            if (c0 > 128u) {
                for (u32 e = 128u + (u32)lane; e < c0; e += 64u) {
                    ulonglong2 Et = tpack[(size_t)t0 * CAP + e];
                    u32 si = (u32)Et.x;
                    if ((sKeepArr[si >> 6] >> (si & 63u)) & 1ull) m |= Et.y;
                }
            }
            u32 lo = wor32((u32)m), hi = wor32((u32)(m >> 32));
            u64 inc = ((u64)rdl32(hi, 63) << 32) | (u64)rdl32(lo, 63);
            u64 alive0 = vw0 & ~inc;
            if (dmw0) {
                u64 d = dmw0 & alive0;
                while (d) {
                    int j = __builtin_ctzll(d);
                    d &= d - 1;
                    if ((alive0 >> j) & 1ull) { alive0 &= ~rdlane64(D0, j); d &= alive0; }
                }
            }
            // ---- word 1 (sources may include word 0 of this super-chunk) ----
            u64 kwA = (h10 == (u32)t0) ? alive0 : K10;
            u64 kwB = (h11 == (u32)t0) ? alive0 : K11;
            m = 0;
            if ((u32)lane < c1 && ((kwA >> (s10 & 63u)) & 1ull)) m = E10.y;
            if ((u32)(lane + 64) < c1 && ((kwB >> (s11 & 63u)) & 1ull)) m |= E11.y;
            if (c1 > 128u) {
                for (u32 e = 128u + (u32)lane; e < c1; e += 64u) {
                    ulonglong2 Et = tpack[(size_t)q1 * CAP + e];
                    u32 si = (u32)Et.x; u32 hh = si >> 6;
                    u64 kw = (hh == (u32)t0) ? alive0 : sKeepArr[hh];
                    if ((kw >> (si & 63u)) & 1ull) m |= Et.y;
                }
            }
            lo = wor32((u32)m); hi = wor32((u32)(m >> 32));
            inc = ((u64)rdl32(hi, 63) << 32) | (u64)rdl32(lo, 63);
            u64 alive1 = vw1 & ~inc;
            if (dmw1) {
                u64 d = dmw1 & alive1;
                while (d) {
                    int j = __builtin_ctzll(d);
                    d &= d - 1;
                    if ((alive1 >> j) & 1ull) { alive1 &= ~rdlane64(D1, j); d &= alive1; }
                }
            }
            // ---- word 2 ----
            kwA = (h20 == (u32)t0) ? alive0 : (h20 == (u32)t1) ? alive1 : K20;
            kwB = (h21 == (u32)t0) ? alive0 : (h21 == (u32)t1) ? alive1 : K21;
            m = 0;
            if ((u32)lane < c2 && ((kwA >> (s20 & 63u)) & 1ull)) m = E20.y;
            if ((u32)(lane + 64) < c2 && ((kwB >> (s21 & 63u)) & 1ull)) m |= E21.y;
            if (c2 > 128u) {
                for (u32 e = 128u + (u32)lane; e < c2; e += 64u) {
                    ulonglong2 Et = tpack[(size_t)q2 * CAP + e];
                    u32 si = (u32)Et.x; u32 hh = si >> 6;
                    u64 kw = (hh == (u32)t0) ? alive0 : (hh == (u32)t1) ? alive1 : sKeepArr[hh];
                    if ((kw >> (si & 63u)) & 1ull) m |= Et.y;
                }
            }
            lo = wor32((u32)m); hi = wor32((u32)(m >> 32));
            inc = ((u64)rdl32(hi, 63) << 32) | (u64)rdl32(lo, 63);
            u64 alive2 = vw2 & ~inc;
            if (dmw2) {
                u64 d = dmw2 & alive2;
                while (d) {
                    int j = __builtin_ctzll(d);
                    d &= d - 1;
                    if ((alive2 >> j) & 1ull) { alive2 &= ~rdlane64(D2, j); d &= alive2; }
                }
            }
            // ---- word 3 ----
            kwA = (h30 == (u32)t0) ? alive0 : (h30 == (u32)t1) ? alive1 : (h30 == (u32)t2) ? alive2 : K30;
            kwB = (h31 == (u32)t0) ? alive0 : (h31 == (u32)t1) ? alive1 : (h31 == (u32)t2) ? alive2 : K31;
            m = 0;
            if ((u32)lane < c3 && ((kwA >> (s30 & 63u)) & 1ull)) m = E30.y;
            if ((u32)(lane + 64) < c3 && ((kwB >> (s31 & 63u)) & 1ull)) m |= E31.y;
            if (c3 > 128u) {
                for (u32 e = 128u + (u32)lane; e < c3; e += 64u) {
                    ulonglong2 Et = tpack[(size_t)q3 * CAP + e];
                    u32 si = (u32)Et.x; u32 hh = si >> 6;
                    u64 kw = (hh == (u32)t0) ? alive0 : (hh == (u32)t1) ? alive1
                           : (hh == (u32)t2) ? alive2 : sKeepArr[hh];
                    if ((kw >> (si & 63u)) & 1ull) m |= Et.y;
                }
            }
            lo = wor32((u32)m); hi = wor32((u32)(m >> 32));
            inc = ((u64)rdl32(hi, 63) << 32) | (u64)rdl32(lo, 63);
            u64 alive3 = vw3 & ~inc;
            if (dmw3) {
                u64 d = dmw3 & alive3;
                while (d) {
                    int j = __builtin_ctzll(d);
                    d &= d - 1;
                    if ((alive3 >> j) & 1ull) { alive3 &= ~rdlane64(D3, j); d &= alive3; }
                }
            }
            // ---- publish 4 words + release ----
            if (lane == 0) {
                sKeepArr[t0] = alive0;
                sKeepArr[t1] = alive1;
                sKeepArr[t2] = alive2;
                sKeepArr[t3] = alive3;
                __hip_atomic_store(&sProg, (u32)(C + 1), __ATOMIC_RELEASE, __HIP_MEMORY_SCOPE_WORKGROUP);
            }
        }
    }
    __syncthreads();
    // ---- fused output phase (all 512 threads) ----
    if (t < NCH) pc[t + 1] = (u32)__popcll(sKeepArr[t]);
    if (t == 0) pc[0] = 0;
    __syncthreads();
    for (int ofs = 1; ofs < NCH; ofs <<= 1) {   // Hillis-Steele inclusive scan over pc[1..NCH]
        int i = t + 1;
        u32 v = 0;
        bool p = (t < NCH) && (i - ofs >= 1);
        if (p) v = pc[i - ofs];
        __syncthreads();
        if (p) pc[i] += v;
        __syncthreads();
    }
    u32 nk = pc[NCH];
    for (int i = t; i < K_TOT; i += 512) {
        int wi = i >> 6, b = i & 63;
        u64 kw = sKeepArr[wi];
        u32 kb = pc[wi] + (u32)__popcll(kw & ((1ull << b) - 1ull));
        bool kp = (kw >> b) & 1ull;
        if (kp) {
            if (kb < 1000u) {
                float4 bx = sB[i];
                out[kb * 4 + 0] = bx.x; out[kb * 4 + 1] = bx.y;
                out[kb * 4 + 2] = bx.z; out[kb * 4 + 3] = bx.w;
                out[4000 + kb] = sS[i];
            }
        } else {
            u32 q = (u32)i - kb;
            u32 slot = nk + q;
            if (slot < 1000u) {
                float4 bx = sB[i];
                out[slot * 4 + 0] = bx.x; out[slot * 4 + 1] = bx.y;
                out[slot * 4 + 2] = bx.z; out[slot * 4 + 3] = bx.w;
                out[4000 + slot] = -INFINITY;
            }
        }
    }
}

// ---------------- workspace layout ----------------
static constexpr size_t al256(size_t x) { return (x + 255) & ~(size_t)255; }
static constexpr size_t KB4 = (size_t)K_TOT * 4;
static constexpr size_t KB16 = (size_t)K_TOT * 16;
// zeroed region:
static constexpr size_t O_RANK = 0;
static constexpr size_t O_PRAW = al256(O_RANK + KB4);
static constexpr size_t O_ECNT = al256(O_PRAW + KB4);
static constexpr size_t O_HIST = al256(O_ECNT + (size_t)NCH * 4);
static constexpr size_t O_CGT = al256(O_HIST + (size_t)3 * 2048 * 4);
static constexpr size_t O_GCNT = al256(O_CGT + 3 * 4);
static constexpr size_t MEMSET_BYTES = al256(O_GCNT + 3 * 4);
// non-zeroed region:
static constexpr size_t O_SEL = MEMSET_BYTES;
static constexpr size_t O_GIDX = al256(O_SEL + KB4);
static constexpr size_t O_GKEY = al256(O_GIDX + (size_t)3 * GCAP * 4);
static constexpr size_t O_CANDB = al256(O_GKEY + (size_t)3 * GCAP * 4);
static constexpr size_t O_CANDS = al256(O_CANDB + KB16);
static constexpr size_t O_CANDV = al256(O_CANDS + KB4);
static constexpr size_t O_CANDA = al256(O_CANDV + KB4);
static constexpr size_t O_SB = al256(O_CANDA + KB4);
static constexpr size_t O_SAREA = al256(O_SB + KB16);
static constexpr size_t O_SS = al256(O_SAREA + KB4);
static constexpr size_t O_SV = al256(O_SS + KB4);
static constexpr size_t O_VW = al256(O_SV + KB4);
static constexpr size_t O_DMASK = al256(O_VW + (size_t)NCH * 8);
static constexpr size_t O_DIAG = al256(O_DMASK + (size_t)NCH * 8);
static constexpr size_t O_EPACK = al256(O_DIAG + (size_t)(NCH * 64) * 8);

extern "C" void kernel_launch(void* const* d_in, const int* in_sizes, int n_in,
                              void* d_out, int out_size, void* d_ws, size_t ws_size,
                              hipStream_t stream) {
    const float* scores = (const float*)d_in[0];
    const float4* deltas = (const float4*)d_in[1];
    const float4* anchors = (const float4*)d_in[2];
    float* out = (float*)d_out;
    char* ws = (char*)d_ws;

    u32* rank = (u32*)(ws + O_RANK);
    u32* Praw = (u32*)(ws + O_PRAW);
    u32* ecnt = (u32*)(ws + O_ECNT);
    u32* hist3 = (u32*)(ws + O_HIST);
    u32* cgt = (u32*)(ws + O_CGT);
    u32* gcnt = (u32*)(ws + O_GCNT);
    u32* sel = (u32*)(ws + O_SEL);
    u32* gidx = (u32*)(ws + O_GIDX);
    u32* gkey = (u32*)(ws + O_GKEY);
    float4* candB = (float4*)(ws + O_CANDB);
    float* candS = (float*)(ws + O_CANDS);
    u32* candV = (u32*)(ws + O_CANDV);
    u32* candA = (u32*)(ws + O_CANDA);
    float4* sB = (float4*)(ws + O_SB);
    float* sArea = (float*)(ws + O_SAREA);
    float* sS = (float*)(ws + O_SS);
    u32* sV = (u32*)(ws + O_SV);
    u64* vwords = (u64*)(ws + O_VW);
    u64* dmask = (u64*)(ws + O_DMASK);
    u64* diag = (u64*)(ws + O_DIAG);
    ulonglong2* epack = (ulonglong2*)(ws + O_EPACK);

    hipMemsetAsync(ws, 0, MEMSET_BYTES, stream);

    const int NBLK = (K_TOT + 255) / 256;  // 33
    k_hist<<<156, 1024, 0, stream>>>(scores, hist3);
    k_gather<<<159, 1024, 0, stream>>>(scores, hist3, sel, cgt, gcnt, gidx, gkey);
    k_final<<<5, 1024, 0, stream>>>(gidx, gkey, gcnt, hist3, sel,
                                    scores, deltas, anchors, candB, candS, candV, candA);
    k_rank_lvl<<<dim3(8, 8, 5), 256, 0, stream>>>(candS, candA, Praw);
    k_rank_glob<<<dim3(NBLK, NBLK), 256, 0, stream>>>(candS, candV, Praw, rank);
    k_scatter<<<NBLK, 256, 0, stream>>>(candB, candS, candV, rank, sB, sArea, sS, sV);
    k_mask<<<dim3(NCH, NBLK), 256, 0, stream>>>(sB, sArea, sV, vwords, diag, ecnt, epack, dmask);
    k_scan<<<1, 512, 0, stream>>>(diag, vwords, ecnt, epack, dmask, sB, sS, out);
}